// Round 3
// baseline (825.651 us; speedup 1.0000x reference)
//
#include <hip/hip_runtime.h>
#include <math.h>

constexpr int D = 64;           // D_IN == D_OUT == 64
constexpr int BNODES = 128;     // nodes per bucket (LDS acc = 128*64*4 = 32 KiB)
constexpr int BSHIFT = 7;
constexpr int PCHUNK = 8192;    // edges per partition block
constexpr int NB_MAX = 1024;    // max buckets supported by LDS arrays

__device__ inline void fma4(float4& a, float s, const float4& w) {
    a.x = fmaf(s, w.x, a.x);
    a.y = fmaf(s, w.y, a.y);
    a.z = fmaf(s, w.z, a.z);
    a.w = fmaf(s, w.w, a.w);
}

__global__ void k_zero_i32(int* __restrict__ p, int n) {
    int i = blockIdx.x * blockDim.x + threadIdx.x;
    if (i < n) p[i] = 0;
}

// cnt[col[e]] += 1
__global__ void k_hist(const int* __restrict__ col, int* __restrict__ cnt, int E) {
    int i = blockIdx.x * blockDim.x + threadIdx.x;
    if (i < E) atomicAdd(&cnt[col[i]], 1);
}

// bcnt[j] = sum of cnt over bucket j's 128 nodes (one wave per bucket)
__global__ __launch_bounds__(256) void k_bsum(const int* __restrict__ cnt,
                                              int* __restrict__ bcnt, int N, int NB) {
    const int j = blockIdx.x * 4 + (threadIdx.x >> 6);
    if (j >= NB) return;
    const int lane = threadIdx.x & 63;
    const int base = j << BSHIFT;
    int s = 0;
    int i0 = base + lane;
    if (i0 < N) s += cnt[i0];
    int i1 = base + 64 + lane;
    if (i1 < N) s += cnt[i1];
#pragma unroll
    for (int off = 1; off < 64; off <<= 1) s += __shfl_xor(s, off, 64);
    if (lane == 0) bcnt[j] = s;
}

// single-block exclusive scan of bcnt -> boff (NB+1 entries), bcur = boff
__global__ __launch_bounds__(1024) void k_bscan(const int* __restrict__ bcnt,
                                                int* __restrict__ boff,
                                                int* __restrict__ bcur, int NB) {
    __shared__ int lds[NB_MAX];
    const int t = threadIdx.x;
    int v = (t < NB) ? bcnt[t] : 0;
    lds[t] = v;
    __syncthreads();
    for (int off = 1; off < NB_MAX; off <<= 1) {
        int y = (t >= off) ? lds[t - off] : 0;
        __syncthreads();
        lds[t] += y;
        __syncthreads();
    }
    if (t < NB) {
        int o = lds[t] - v;     // exclusive
        boff[t] = o;
        bcur[t] = o;
    }
    if (t == NB_MAX - 1) boff[NB] = lds[NB_MAX - 1];
}

// coarse partition: scatter packed (r<<7 | c&127) into per-bucket segments.
// Per-block LDS hist -> one global cursor reservation per bucket -> run-local writes.
__global__ __launch_bounds__(256) void k_partition(
        const int* __restrict__ ei, int* __restrict__ bcur,
        unsigned* __restrict__ ebuf, int E, int NB) {
    __shared__ int lh[NB_MAX];
    __shared__ int lb[NB_MAX];
    const int t = threadIdx.x;
    for (int j = t; j < NB; j += 256) lh[j] = 0;
    __syncthreads();
    const int e0 = blockIdx.x * PCHUNK;
    const int e1 = min(e0 + PCHUNK, E);
    for (int e = e0 + t; e < e1; e += 256)
        atomicAdd(&lh[ei[E + e] >> BSHIFT], 1);
    __syncthreads();
    for (int j = t; j < NB; j += 256) {
        int n = lh[j];
        lb[j] = n ? atomicAdd(&bcur[j], n) : 0;
        lh[j] = 0;
    }
    __syncthreads();
    for (int e = e0 + t; e < e1; e += 256) {
        int r = ei[e];
        int c = ei[E + e];
        int bkt = c >> BSHIFT;
        int rank = atomicAdd(&lh[bkt], 1);
        ebuf[lb[bkt] + rank] = ((unsigned)r << BSHIFT) | (unsigned)(c & (BNODES - 1));
    }
}

// h = x @ W ; g = dinv * h
__global__ __launch_bounds__(256) void k_gemm_scale(
        const float* __restrict__ x, const float* __restrict__ W,
        const int* __restrict__ cnt, float* __restrict__ g, int N) {
    __shared__ float4 Wl[D * D / 4];     // 16 KiB
    const int tid = threadIdx.x;
    const float4* W4 = reinterpret_cast<const float4*>(W);
    for (int i = tid; i < D * D / 4; i += 256) Wl[i] = W4[i];
    __syncthreads();

    const int node = blockIdx.x * 256 + tid;
    if (node >= N) return;

    const float4* xr = reinterpret_cast<const float4*>(x + (size_t)node * D);
    float4 a[16];
#pragma unroll
    for (int j = 0; j < 16; ++j) a[j] = make_float4(0.f, 0.f, 0.f, 0.f);

    for (int k4 = 0; k4 < 16; ++k4) {
        const float4 xv = xr[k4];
#pragma unroll
        for (int j4 = 0; j4 < 16; ++j4) {
            fma4(a[j4], xv.x, Wl[(4 * k4 + 0) * 16 + j4]);
            fma4(a[j4], xv.y, Wl[(4 * k4 + 1) * 16 + j4]);
            fma4(a[j4], xv.z, Wl[(4 * k4 + 2) * 16 + j4]);
            fma4(a[j4], xv.w, Wl[(4 * k4 + 3) * 16 + j4]);
        }
    }

    const float dinv = rsqrtf((float)(cnt[node] + 1));
    float4* g4 = reinterpret_cast<float4*>(g + (size_t)node * D);
#pragma unroll
    for (int j4 = 0; j4 < 16; ++j4) {
        float4 v = a[j4];
        v.x *= dinv; v.y *= dinv; v.z *= dinv; v.w *= dinv;
        g4[j4] = v;
    }
}

// one block per bucket: LDS acc seeded with g (self loop), gather+ds_add per edge,
// dense epilogue out = dinv*acc + b
__global__ __launch_bounds__(256) void k_breduce(
        const int* __restrict__ boff, const unsigned* __restrict__ ebuf,
        const float* __restrict__ g, const int* __restrict__ cnt,
        const float* __restrict__ b, float* __restrict__ out, int N) {
    __shared__ float acc[BNODES * D];    // 32 KiB
    const int j = blockIdx.x;
    const int base = j << BSHIFT;
    const int nn = min(BNODES, N - base);
    const int t = threadIdx.x;

    const float4* g4 = reinterpret_cast<const float4*>(g);
    float4* a4 = reinterpret_cast<float4*>(acc);
    for (int i = t; i < nn * 16; i += 256) a4[i] = g4[(size_t)base * 16 + i];
    __syncthreads();

    const int lane = t & 63;
    const int wave = t >> 6;
    const int grp  = lane >> 4;    // 4 edges per wave per iter
    const int fl   = lane & 15;    // float4 slot within row

    const int i1 = boff[j + 1];
#pragma unroll 2
    for (int i = boff[j] + wave * 4 + grp; i < i1; i += 16) {
        const unsigned e = ebuf[i];
        const int cl = e & (BNODES - 1);
        const int r  = (int)(e >> BSHIFT);
        const float4 v = g4[(size_t)r * 16 + fl];
        float* ap = &acc[cl * D + fl * 4];
        atomicAdd(ap + 0, v.x);
        atomicAdd(ap + 1, v.y);
        atomicAdd(ap + 2, v.z);
        atomicAdd(ap + 3, v.w);
    }
    __syncthreads();

    for (int idx = t; idx < nn * 16; idx += 256) {
        const int node = idx >> 4;
        const float dinv = rsqrtf((float)(cnt[base + node] + 1));
        const float4 v = a4[idx];
        const float4 bv = reinterpret_cast<const float4*>(b)[idx & 15];
        float4 o;
        o.x = fmaf(dinv, v.x, bv.x);
        o.y = fmaf(dinv, v.y, bv.y);
        o.z = fmaf(dinv, v.z, bv.z);
        o.w = fmaf(dinv, v.w, bv.w);
        reinterpret_cast<float4*>(out)[(size_t)(base + node) * 16 + (idx & 15)] = o;
    }
}

extern "C" void kernel_launch(void* const* d_in, const int* in_sizes, int n_in,
                              void* d_out, int out_size, void* d_ws, size_t ws_size,
                              hipStream_t stream) {
    const float* x  = (const float*)d_in[0];
    const int*   ei = (const int*)d_in[1];
    const float* W  = (const float*)d_in[2];
    const float* b  = (const float*)d_in[3];
    float* out = (float*)d_out;

    const int N = in_sizes[0] / D;     // 100000
    const int E = in_sizes[1] / 2;     // 1600000
    const int NB = (N + BNODES - 1) >> BSHIFT;   // 782

    // ws layout
    float*    g    = (float*)d_ws;                      // N*D floats (25.6 MB)
    int*      cnt  = (int*)(g + (size_t)N * D);         // N
    int*      bcnt = cnt + N;                           // NB
    int*      boff = bcnt + NB;                         // NB+1
    int*      bcur = boff + NB + 1;                     // NB
    unsigned* ebuf = (unsigned*)(bcur + NB);            // E (6.4 MB)

    k_zero_i32 <<<(N + 255) / 256, 256, 0, stream>>>(cnt, N);
    k_hist     <<<(E + 255) / 256, 256, 0, stream>>>(ei + E, cnt, E);
    k_bsum     <<<(NB + 3) / 4, 256, 0, stream>>>(cnt, bcnt, N, NB);
    k_bscan    <<<1, NB_MAX, 0, stream>>>(bcnt, boff, bcur, NB);
    k_partition<<<(E + PCHUNK - 1) / PCHUNK, 256, 0, stream>>>(ei, bcur, ebuf, E, NB);
    k_gemm_scale<<<(N + 255) / 256, 256, 0, stream>>>(x, W, cnt, g, N);
    k_breduce  <<<NB, 256, 0, stream>>>(boff, ebuf, g, cnt, b, out, N);
}

// Round 4
// 154.130 us; speedup vs baseline: 5.3569x; 5.3569x over previous
//
#include <hip/hip_runtime.h>
#include <hip/hip_fp16.h>
#include <math.h>

constexpr int D = 64;           // D_IN == D_OUT == 64
constexpr int BNODES = 128;     // nodes per bucket
constexpr int BSHIFT = 7;
constexpr int PCHUNK = 8192;    // edges per partition/hist block
constexpr int NB_MAX = 1024;    // max buckets (N <= 131072)

__device__ inline void fma4(float4& a, float s, const float4& w) {
    a.x = fmaf(s, w.x, a.x);
    a.y = fmaf(s, w.y, a.y);
    a.z = fmaf(s, w.z, a.z);
    a.w = fmaf(s, w.w, a.w);
}

__device__ inline unsigned pack2(float a, float b) {
    __half2 h = __floats2half2_rn(a, b);
    return *reinterpret_cast<unsigned*>(&h);
}

__device__ inline float4 unpack4(uint2 u) {
    __half2 h0 = *reinterpret_cast<__half2*>(&u.x);
    __half2 h1 = *reinterpret_cast<__half2*>(&u.y);
    float2 f0 = __half22float2(h0);
    float2 f1 = __half22float2(h1);
    return make_float4(f0.x, f0.y, f1.x, f1.y);
}

__global__ void k_zero_i32(int* __restrict__ p, int n) {
    int i = blockIdx.x * blockDim.x + threadIdx.x;
    if (i < n) p[i] = 0;
}

// bucket histogram: per-block LDS hist (native int LDS atomics), one global add per bucket
__global__ __launch_bounds__(256) void k_bhist(const int* __restrict__ col,
                                               int* __restrict__ bcnt, int E, int NB) {
    __shared__ int lh[NB_MAX];
    const int t = threadIdx.x;
    for (int j = t; j < NB; j += 256) lh[j] = 0;
    __syncthreads();
    const int e0 = blockIdx.x * PCHUNK;
    const int e1 = min(e0 + PCHUNK, E);
    for (int e = e0 + t; e < e1; e += 256)
        atomicAdd(&lh[col[e] >> BSHIFT], 1);
    __syncthreads();
    for (int j = t; j < NB; j += 256) {
        int v = lh[j];
        if (v) atomicAdd(&bcnt[j], v);
    }
}

// single-block exclusive scan of bcnt -> boff (NB+1), bcur = boff
__global__ __launch_bounds__(1024) void k_bscan(const int* __restrict__ bcnt,
                                                int* __restrict__ boff,
                                                int* __restrict__ bcur, int NB) {
    __shared__ int lds[NB_MAX];
    const int t = threadIdx.x;
    int v = (t < NB) ? bcnt[t] : 0;
    lds[t] = v;
    __syncthreads();
    for (int off = 1; off < NB_MAX; off <<= 1) {
        int y = (t >= off) ? lds[t - off] : 0;
        __syncthreads();
        lds[t] += y;
        __syncthreads();
    }
    if (t < NB) {
        int o = lds[t] - v;
        boff[t] = o;
        bcur[t] = o;
    }
    if (t == NB_MAX - 1) boff[NB] = lds[NB_MAX - 1];
}

// coarse partition: packed (r<<7 | c&127) into per-bucket segments via run reservation
__global__ __launch_bounds__(256) void k_partition(
        const int* __restrict__ ei, int* __restrict__ bcur,
        unsigned* __restrict__ ebuf, int E, int NB) {
    __shared__ int lh[NB_MAX];
    __shared__ int lb[NB_MAX];
    const int t = threadIdx.x;
    for (int j = t; j < NB; j += 256) lh[j] = 0;
    __syncthreads();
    const int e0 = blockIdx.x * PCHUNK;
    const int e1 = min(e0 + PCHUNK, E);
    for (int e = e0 + t; e < e1; e += 256)
        atomicAdd(&lh[ei[E + e] >> BSHIFT], 1);
    __syncthreads();
    for (int j = t; j < NB; j += 256) {
        int n = lh[j];
        lb[j] = n ? atomicAdd(&bcur[j], n) : 0;
        lh[j] = 0;
    }
    __syncthreads();
    for (int e = e0 + t; e < e1; e += 256) {
        int r = ei[e];
        int c = ei[E + e];
        int bkt = c >> BSHIFT;
        int rank = atomicAdd(&lh[bkt], 1);
        ebuf[lb[bkt] + rank] = ((unsigned)r << BSHIFT) | (unsigned)(c & (BNODES - 1));
    }
}

// bucket segment -> exact per-node CSR (int LDS atomics + LDS scan only).
// Also emits cnt[] (per-node degree) and offs[] (CSR start).
__global__ __launch_bounds__(256) void k_csr(
        const int* __restrict__ boff, const unsigned* __restrict__ ebuf,
        int* __restrict__ cnt, int* __restrict__ offs,
        int* __restrict__ srcIdx, int N) {
    __shared__ int lh[BNODES];
    __shared__ int sc[BNODES];
    __shared__ int lcur[BNODES];
    const int j = blockIdx.x;
    const int t = threadIdx.x;
    const int s0 = boff[j];
    const int s1 = boff[j + 1];

    if (t < BNODES) lh[t] = 0;
    __syncthreads();
    for (int i = s0 + t; i < s1; i += 256)
        atomicAdd(&lh[ebuf[i] & (BNODES - 1)], 1);
    __syncthreads();
    if (t < BNODES) sc[t] = lh[t];
    __syncthreads();
    for (int off = 1; off < BNODES; off <<= 1) {
        int y = 0;
        if (t < BNODES && t >= off) y = sc[t - off];
        __syncthreads();
        if (t < BNODES && t >= off) sc[t] += y;
        __syncthreads();
    }
    if (t < BNODES) {
        const int excl = sc[t] - lh[t];
        lcur[t] = excl;
        const int node = (j << BSHIFT) + t;
        if (node < N) {
            cnt[node]  = lh[t];
            offs[node] = s0 + excl;
        }
    }
    __syncthreads();
    for (int i = s0 + t; i < s1; i += 256) {
        const unsigned code = ebuf[i];
        const int c = code & (BNODES - 1);
        const int rank = atomicAdd(&lcur[c], 1);
        srcIdx[s0 + rank] = (int)(code >> BSHIFT);
    }
}

// h = x @ W ; g(fp16) = dinv * h
__global__ __launch_bounds__(256) void k_gemm_scale(
        const float* __restrict__ x, const float* __restrict__ W,
        const int* __restrict__ cnt, __half* __restrict__ gh, int N) {
    __shared__ float4 Wl[D * D / 4];     // 16 KiB
    const int tid = threadIdx.x;
    const float4* W4 = reinterpret_cast<const float4*>(W);
    for (int i = tid; i < D * D / 4; i += 256) Wl[i] = W4[i];
    __syncthreads();

    const int node = blockIdx.x * 256 + tid;
    if (node >= N) return;

    const float4* xr = reinterpret_cast<const float4*>(x + (size_t)node * D);
    float4 a[16];
#pragma unroll
    for (int j = 0; j < 16; ++j) a[j] = make_float4(0.f, 0.f, 0.f, 0.f);

    for (int k4 = 0; k4 < 16; ++k4) {
        const float4 xv = xr[k4];
#pragma unroll
        for (int j4 = 0; j4 < 16; ++j4) {
            fma4(a[j4], xv.x, Wl[(4 * k4 + 0) * 16 + j4]);
            fma4(a[j4], xv.y, Wl[(4 * k4 + 1) * 16 + j4]);
            fma4(a[j4], xv.z, Wl[(4 * k4 + 2) * 16 + j4]);
            fma4(a[j4], xv.w, Wl[(4 * k4 + 3) * 16 + j4]);
        }
    }

    const float dinv = rsqrtf((float)(cnt[node] + 1));
    uint4* out4 = reinterpret_cast<uint4*>(gh + (size_t)node * D);
#pragma unroll
    for (int p = 0; p < 8; ++p) {
        const float4 v0 = a[2 * p];
        const float4 v1 = a[2 * p + 1];
        uint4 u;
        u.x = pack2(v0.x * dinv, v0.y * dinv);
        u.y = pack2(v0.z * dinv, v0.w * dinv);
        u.z = pack2(v1.x * dinv, v1.y * dinv);
        u.w = pack2(v1.z * dinv, v1.w * dinv);
        out4[p] = u;
    }
}

// one wave per node, 4 lane-groups of 16 process 4 edges/iter, fp16 gathers, fp32 accum
__global__ __launch_bounds__(256) void k_reduce(
        const int* __restrict__ offs, const int* __restrict__ cnt,
        const int* __restrict__ srcIdx, const __half* __restrict__ gh,
        const float* __restrict__ b, float* __restrict__ out, int N) {
    const int node = blockIdx.x * 4 + (threadIdx.x >> 6);
    if (node >= N) return;
    const int lane = threadIdx.x & 63;
    const int grp  = lane >> 4;   // edge slot 0..3
    const int fl   = lane & 15;   // uint2 slot (4 halves) within row

    const uint2* g2 = reinterpret_cast<const uint2*>(gh);
    const int beg = offs[node];
    const int num = cnt[node];

    float4 acc = make_float4(0.f, 0.f, 0.f, 0.f);
    if (grp == 0) acc = unpack4(g2[(size_t)node * 16 + fl]);   // self loop

#pragma unroll 2
    for (int i = beg + grp; i < beg + num; i += 4) {
        const int r = srcIdx[i];
        const float4 v = unpack4(g2[(size_t)r * 16 + fl]);
        acc.x += v.x; acc.y += v.y; acc.z += v.z; acc.w += v.w;
    }

#pragma unroll
    for (int off = 16; off <= 32; off <<= 1) {
        acc.x += __shfl_xor(acc.x, off, 64);
        acc.y += __shfl_xor(acc.y, off, 64);
        acc.z += __shfl_xor(acc.z, off, 64);
        acc.w += __shfl_xor(acc.w, off, 64);
    }

    if (grp == 0) {
        const float dinv = rsqrtf((float)(num + 1));
        const float4 bb = reinterpret_cast<const float4*>(b)[fl];
        float4 o;
        o.x = fmaf(dinv, acc.x, bb.x);
        o.y = fmaf(dinv, acc.y, bb.y);
        o.z = fmaf(dinv, acc.z, bb.z);
        o.w = fmaf(dinv, acc.w, bb.w);
        reinterpret_cast<float4*>(out)[(size_t)node * 16 + fl] = o;
    }
}

extern "C" void kernel_launch(void* const* d_in, const int* in_sizes, int n_in,
                              void* d_out, int out_size, void* d_ws, size_t ws_size,
                              hipStream_t stream) {
    const float* x  = (const float*)d_in[0];
    const int*   ei = (const int*)d_in[1];
    const float* W  = (const float*)d_in[2];
    const float* b  = (const float*)d_in[3];
    float* out = (float*)d_out;

    const int N = in_sizes[0] / D;     // 100000
    const int E = in_sizes[1] / 2;     // 1600000
    const int NB = (N + BNODES - 1) >> BSHIFT;   // 782
    const int blocksP = (E + PCHUNK - 1) / PCHUNK;

    // ws layout
    __half* gh     = (__half*)d_ws;                       // N*64 halves (12.8 MB)
    int*    cnt    = (int*)(gh + (size_t)N * D);          // N
    int*    offs   = cnt + N;                             // N
    int*    bcnt   = offs + N;                            // NB
    int*    boff   = bcnt + NB;                           // NB+1
    int*    bcur   = boff + NB + 1;                       // NB
    unsigned* ebuf = (unsigned*)(bcur + NB);              // E (6.4 MB)
    int*    srcIdx = (int*)(ebuf + E);                    // E (6.4 MB)

    k_zero_i32 <<<(NB + 255) / 256, 256, 0, stream>>>(bcnt, NB);
    k_bhist    <<<blocksP, 256, 0, stream>>>(ei + E, bcnt, E, NB);
    k_bscan    <<<1, NB_MAX, 0, stream>>>(bcnt, boff, bcur, NB);
    k_partition<<<blocksP, 256, 0, stream>>>(ei, bcur, ebuf, E, NB);
    k_csr      <<<NB, 256, 0, stream>>>(boff, ebuf, cnt, offs, srcIdx, N);
    k_gemm_scale<<<(N + 255) / 256, 256, 0, stream>>>(x, W, cnt, gh, N);
    k_reduce   <<<(N + 3) / 4, 256, 0, stream>>>(offs, cnt, srcIdx, gh, b, out, N);
}

// Round 5
// 126.081 us; speedup vs baseline: 6.5486x; 1.2225x over previous
//
#include <hip/hip_runtime.h>
#include <hip/hip_fp16.h>
#include <math.h>

constexpr int D = 64;           // D_IN == D_OUT == 64
constexpr int BNODES = 128;     // nodes per bucket
constexpr int BSHIFT = 7;
constexpr int PCHUNK = 8192;    // edges per partition/hist block
constexpr int NB_MAX = 1024;    // max buckets (N <= 131072)

typedef _Float16 half8 __attribute__((ext_vector_type(8)));
typedef float floatx4 __attribute__((ext_vector_type(4)));

__global__ void k_zero_i32(int* __restrict__ p, int n) {
    int i = blockIdx.x * blockDim.x + threadIdx.x;
    if (i < n) p[i] = 0;
}

// bucket histogram: per-block LDS hist (int LDS atomics), one global add per bucket
__global__ __launch_bounds__(256) void k_bhist(const int* __restrict__ col,
                                               int* __restrict__ bcnt, int E, int NB) {
    __shared__ int lh[NB_MAX];
    const int t = threadIdx.x;
    for (int j = t; j < NB; j += 256) lh[j] = 0;
    __syncthreads();
    const int e0 = blockIdx.x * PCHUNK;
    const int e1 = min(e0 + PCHUNK, E);
    for (int e = e0 + t; e < e1; e += 256)
        atomicAdd(&lh[col[e] >> BSHIFT], 1);
    __syncthreads();
    for (int j = t; j < NB; j += 256) {
        int v = lh[j];
        if (v) atomicAdd(&bcnt[j], v);
    }
}

// single-block exclusive scan of bcnt -> boff (NB+1), bcur = boff
__global__ __launch_bounds__(1024) void k_bscan(const int* __restrict__ bcnt,
                                                int* __restrict__ boff,
                                                int* __restrict__ bcur, int NB) {
    __shared__ int lds[NB_MAX];
    const int t = threadIdx.x;
    int v = (t < NB) ? bcnt[t] : 0;
    lds[t] = v;
    __syncthreads();
    for (int off = 1; off < NB_MAX; off <<= 1) {
        int y = (t >= off) ? lds[t - off] : 0;
        __syncthreads();
        lds[t] += y;
        __syncthreads();
    }
    if (t < NB) {
        int o = lds[t] - v;
        boff[t] = o;
        bcur[t] = o;
    }
    if (t == NB_MAX - 1) boff[NB] = lds[NB_MAX - 1];
}

// coarse partition: packed (r<<7 | c&127) into per-bucket segments via run reservation
__global__ __launch_bounds__(256) void k_partition(
        const int* __restrict__ ei, int* __restrict__ bcur,
        unsigned* __restrict__ ebuf, int E, int NB) {
    __shared__ int lh[NB_MAX];
    __shared__ int lb[NB_MAX];
    const int t = threadIdx.x;
    for (int j = t; j < NB; j += 256) lh[j] = 0;
    __syncthreads();
    const int e0 = blockIdx.x * PCHUNK;
    const int e1 = min(e0 + PCHUNK, E);
    for (int e = e0 + t; e < e1; e += 256)
        atomicAdd(&lh[ei[E + e] >> BSHIFT], 1);
    __syncthreads();
    for (int j = t; j < NB; j += 256) {
        int n = lh[j];
        lb[j] = n ? atomicAdd(&bcur[j], n) : 0;
        lh[j] = 0;
    }
    __syncthreads();
    for (int e = e0 + t; e < e1; e += 256) {
        int r = ei[e];
        int c = ei[E + e];
        int bkt = c >> BSHIFT;
        int rank = atomicAdd(&lh[bkt], 1);
        ebuf[lb[bkt] + rank] = ((unsigned)r << BSHIFT) | (unsigned)(c & (BNODES - 1));
    }
}

// bucket segment -> exact per-node CSR (int LDS atomics + LDS scan only)
__global__ __launch_bounds__(256) void k_csr(
        const int* __restrict__ boff, const unsigned* __restrict__ ebuf,
        int* __restrict__ cnt, int* __restrict__ offs,
        int* __restrict__ srcIdx, int N) {
    __shared__ int lh[BNODES];
    __shared__ int sc[BNODES];
    __shared__ int lcur[BNODES];
    const int j = blockIdx.x;
    const int t = threadIdx.x;
    const int s0 = boff[j];
    const int s1 = boff[j + 1];

    if (t < BNODES) lh[t] = 0;
    __syncthreads();
    for (int i = s0 + t; i < s1; i += 256)
        atomicAdd(&lh[ebuf[i] & (BNODES - 1)], 1);
    __syncthreads();
    if (t < BNODES) sc[t] = lh[t];
    __syncthreads();
    for (int off = 1; off < BNODES; off <<= 1) {
        int y = 0;
        if (t < BNODES && t >= off) y = sc[t - off];
        __syncthreads();
        if (t < BNODES && t >= off) sc[t] += y;
        __syncthreads();
    }
    if (t < BNODES) {
        const int excl = sc[t] - lh[t];
        lcur[t] = excl;
        const int node = (j << BSHIFT) + t;
        if (node < N) {
            cnt[node]  = lh[t];
            offs[node] = s0 + excl;
        }
    }
    __syncthreads();
    for (int i = s0 + t; i < s1; i += 256) {
        const unsigned code = ebuf[i];
        const int c = code & (BNODES - 1);
        const int rank = atomicAdd(&lcur[c], 1);
        srcIdx[s0 + rank] = (int)(code >> BSHIFT);
    }
}

// Wt[j][k] = (f16) W[k][j]  — pre-transposed f16 weights for MFMA B-frags
__global__ __launch_bounds__(256) void k_wprep(const float* __restrict__ W,
                                               __half* __restrict__ Wt) {
    const int t = threadIdx.x;
    for (int idx = t; idx < D * D; idx += 256) {
        const int j = idx >> 6;
        const int k = idx & 63;
        Wt[idx] = __float2half(W[k * D + j]);
    }
}

// h = x @ W via f16 MFMA ; gh(fp16) = dinv * h
// One wave per 16-node tile. A from global f32 (converted in-reg), B from Wt (L1).
__global__ __launch_bounds__(256) void k_gemm_mfma(
        const float* __restrict__ x, const __half* __restrict__ Wt,
        const int* __restrict__ cnt, __half* __restrict__ gh, int N) {
    const int tile = (blockIdx.x * 256 + threadIdx.x) >> 6;
    const int nt = N >> 4;                 // N % 16 == 0 for this problem
    if (tile >= nt) return;
    const int lane = threadIdx.x & 63;
    const int r16  = lane & 15;            // A-row / B-col / D-col
    const int kq   = lane >> 4;            // 0..3

    // B fragments: 4 col-tiles x 2 k-steps; B[k][j]: j=lane&15, k=kq*8+b (+32*s)
    const _Float16* wt = (const _Float16*)Wt;
    half8 bf[4][2];
#pragma unroll
    for (int jt = 0; jt < 4; ++jt)
#pragma unroll
        for (int s = 0; s < 2; ++s)
            bf[jt][s] = *(const half8*)(wt + (jt * 16 + r16) * D + s * 32 + kq * 8);

    // A fragments: A[i][k]: i=lane&15, k=kq*8+b (+32*s); load f32, convert in-reg
    half8 af[2];
#pragma unroll
    for (int s = 0; s < 2; ++s) {
        const float4* xp = reinterpret_cast<const float4*>(
            x + (size_t)(tile * 16 + r16) * D + s * 32 + kq * 8);
        const float4 x0 = xp[0];
        const float4 x1 = xp[1];
        half8 a;
        a[0] = (_Float16)x0.x; a[1] = (_Float16)x0.y;
        a[2] = (_Float16)x0.z; a[3] = (_Float16)x0.w;
        a[4] = (_Float16)x1.x; a[5] = (_Float16)x1.y;
        a[6] = (_Float16)x1.z; a[7] = (_Float16)x1.w;
        af[s] = a;
    }

    floatx4 acc[4];
#pragma unroll
    for (int jt = 0; jt < 4; ++jt) {
        acc[jt] = (floatx4){0.f, 0.f, 0.f, 0.f};
        acc[jt] = __builtin_amdgcn_mfma_f32_16x16x32_f16(af[0], bf[jt][0], acc[jt], 0, 0, 0);
        acc[jt] = __builtin_amdgcn_mfma_f32_16x16x32_f16(af[1], bf[jt][1], acc[jt], 0, 0, 0);
    }

    // D: col = lane&15 (= r16), row = kq*4 + reg
#pragma unroll
    for (int r = 0; r < 4; ++r) {
        const int node = tile * 16 + kq * 4 + r;
        const float dinv = rsqrtf((float)(cnt[node] + 1));
#pragma unroll
        for (int jt = 0; jt < 4; ++jt)
            gh[(size_t)node * D + jt * 16 + r16] = __float2half(acc[jt][r] * dinv);
    }
}

__device__ inline void unpack8(uint4 u, float* f) {
    float2 a = __half22float2(*reinterpret_cast<__half2*>(&u.x));
    float2 b = __half22float2(*reinterpret_cast<__half2*>(&u.y));
    float2 c = __half22float2(*reinterpret_cast<__half2*>(&u.z));
    float2 d = __half22float2(*reinterpret_cast<__half2*>(&u.w));
    f[0] = a.x; f[1] = a.y; f[2] = b.x; f[3] = b.y;
    f[4] = c.x; f[5] = c.y; f[6] = d.x; f[7] = d.y;
}

// one wave per node, 8 lane-groups of 8 process 8 edges/iter, uint4 (16B) gathers
__global__ __launch_bounds__(256) void k_reduce(
        const int* __restrict__ offs, const int* __restrict__ cnt,
        const int* __restrict__ srcIdx, const __half* __restrict__ gh,
        const float* __restrict__ b, float* __restrict__ out, int N) {
    const int node = blockIdx.x * 4 + (threadIdx.x >> 6);
    if (node >= N) return;
    const int lane = threadIdx.x & 63;
    const int grp  = lane >> 3;   // edge slot 0..7
    const int fl   = lane & 7;    // uint4 slot (8 halves) within row

    const uint4* g4 = reinterpret_cast<const uint4*>(gh);
    const int beg = offs[node];
    const int num = cnt[node];

    float acc[8] = {0.f, 0.f, 0.f, 0.f, 0.f, 0.f, 0.f, 0.f};
    if (grp == 0) unpack8(g4[(size_t)node * 8 + fl], acc);   // self loop

    for (int i = beg + grp; i < beg + num; i += 8) {
        const int r = srcIdx[i];
        float v[8];
        unpack8(g4[(size_t)r * 8 + fl], v);
#pragma unroll
        for (int q = 0; q < 8; ++q) acc[q] += v[q];
    }

#pragma unroll
    for (int off = 8; off <= 32; off <<= 1)
#pragma unroll
        for (int q = 0; q < 8; ++q)
            acc[q] += __shfl_xor(acc[q], off, 64);

    if (grp == 0) {
        const float dinv = rsqrtf((float)(num + 1));
        const float4* b4 = reinterpret_cast<const float4*>(b);
        float4* o4 = reinterpret_cast<float4*>(out);
#pragma unroll
        for (int h = 0; h < 2; ++h) {
            const float4 bb = b4[fl * 2 + h];
            float4 o;
            o.x = fmaf(dinv, acc[4 * h + 0], bb.x);
            o.y = fmaf(dinv, acc[4 * h + 1], bb.y);
            o.z = fmaf(dinv, acc[4 * h + 2], bb.z);
            o.w = fmaf(dinv, acc[4 * h + 3], bb.w);
            o4[(size_t)node * 16 + fl * 2 + h] = o;
        }
    }
}

extern "C" void kernel_launch(void* const* d_in, const int* in_sizes, int n_in,
                              void* d_out, int out_size, void* d_ws, size_t ws_size,
                              hipStream_t stream) {
    const float* x  = (const float*)d_in[0];
    const int*   ei = (const int*)d_in[1];
    const float* W  = (const float*)d_in[2];
    const float* b  = (const float*)d_in[3];
    float* out = (float*)d_out;

    const int N = in_sizes[0] / D;     // 100000
    const int E = in_sizes[1] / 2;     // 1600000
    const int NB = (N + BNODES - 1) >> BSHIFT;   // 782
    const int blocksP = (E + PCHUNK - 1) / PCHUNK;

    // ws layout
    __half*   gh     = (__half*)d_ws;                     // N*64 halves (12.8 MB)
    int*      cnt    = (int*)(gh + (size_t)N * D);        // N
    int*      offs   = cnt + N;                           // N
    int*      bcnt   = offs + N;                          // NB
    int*      boff   = bcnt + NB;                         // NB+1
    int*      bcur   = boff + NB + 1;                     // NB
    unsigned* ebuf   = (unsigned*)(bcur + NB);            // E (6.4 MB)
    int*      srcIdx = (int*)(ebuf + E);                  // E (6.4 MB)
    __half*   Wt     = (__half*)(srcIdx + E);             // 4096 halves (8 KB)

    k_wprep    <<<1, 256, 0, stream>>>(W, Wt);
    k_zero_i32 <<<(NB + 255) / 256, 256, 0, stream>>>(bcnt, NB);
    k_bhist    <<<blocksP, 256, 0, stream>>>(ei + E, bcnt, E, NB);
    k_bscan    <<<1, NB_MAX, 0, stream>>>(bcnt, boff, bcur, NB);
    k_partition<<<blocksP, 256, 0, stream>>>(ei, bcur, ebuf, E, NB);
    k_csr      <<<NB, 256, 0, stream>>>(boff, ebuf, cnt, offs, srcIdx, N);
    k_gemm_mfma<<<((N / 16) * 64 + 255) / 256, 256, 0, stream>>>(x, Wt, cnt, gh, N);
    k_reduce   <<<(N + 3) / 4, 256, 0, stream>>>(offs, cnt, srcIdx, gh, b, out, N);
}